// Round 7
// baseline (280.665 us; speedup 1.0000x reference)
//
#include <hip/hip_runtime.h>
#include <math.h>

constexpr int B = 16, T = 2048, C = 256;

typedef float vfloat4 __attribute__((ext_vector_type(4)));

// ---------------------------------------------------------------------------
// Kernel 1: fuse conv_w [C_out, C_in, 3] with lin_w [C_out] -> w2f[3*C], and
// bias2 = lin_w . conv_b + lin_b. One wave per output element (769 waves).
// Also zeroes the per-batch arrival counters used by pdot_scan (runs every
// call -> deterministic across graph replays).
// ---------------------------------------------------------------------------
__global__ void w2_kernel(const float* __restrict__ conv_w,
                          const float* __restrict__ conv_b,
                          const float* __restrict__ lin_w,
                          const float* __restrict__ lin_b,
                          float* __restrict__ w2f,
                          float* __restrict__ bias2,
                          int* __restrict__ done) {
    int gid  = blockIdx.x * blockDim.x + threadIdx.x;
    if (gid < B) done[gid] = 0;
    int wv   = gid >> 6;
    int lane = gid & 63;
    if (wv > 768) return;
    float s = 0.f;
    if (wv < 768) {
        int i = wv & 255, k = wv >> 8;   // wv = k*256 + i
#pragma unroll
        for (int m = 0; m < 4; ++m) {
            int o = lane + 64 * m;
            s = fmaf(lin_w[o], conv_w[((size_t)o * C + i) * 3 + k], s);
        }
    } else {
#pragma unroll
        for (int m = 0; m < 4; ++m) {
            int o = lane + 64 * m;
            s = fmaf(lin_w[o], conv_b[o], s);
        }
    }
#pragma unroll
    for (int off = 32; off; off >>= 1) s += __shfl_down(s, off);
    if (lane == 0) {
        if (wv < 768) w2f[wv] = s;
        else          *bias2 = s + lin_b[0];
    }
}

// ---------------------------------------------------------------------------
// Kernel 2: fused pdot + per-batch scan ("last arriver does the scan").
// Phase A (all 8192 blocks): one wave per frame computes
//   P_k[bt] = dot(w2f[k], h[b,t,:])   (h read exactly once, 32 MB)
// then __threadfence + atomicAdd(done[b]). The block that sees old==511
// (all 512 blocks of its batch done) acquires and runs the whole-batch scan:
//   alpha[t] = sigmoid(P0[t-1]+P1[t]+P2[t+1]+bias2)
//   aa_t == S_t - floor(S_t) with S = prefix-sum(alpha), so a fire at t is an
//   integer crossing; emits F/A1/REM/Kaux + per-batch loss partial.
// F/A1/REM alias P0/P1/P2 (reads complete before writes, same block, barrier;
// other batches touch disjoint ranges). No spinning anywhere -> no
// dispatch-order dependence.
// ---------------------------------------------------------------------------
__global__ void pdot_scan(const float* __restrict__ h,
                          const float* __restrict__ w2f,
                          const float* __restrict__ bias2,
                          float* P0, float* P1, float* P2,  // alias F/A1/REM
                          float* alpha,
                          int*   Kaux,
                          float* lossP,
                          int*   done) {
    int gid  = blockIdx.x * blockDim.x + threadIdx.x;
    int wv   = gid >> 6;          // global frame index (b*T + t)
    int lane = gid & 63;
    int b    = blockIdx.x >> 9;   // 512 blocks per batch
    int tid  = threadIdx.x;

    // ---- phase A: partial dots, one wave per frame ----
    {
        const float4* w4 = (const float4*)w2f;
        float4 w0 = w4[lane], w1 = w4[64 + lane], w2v = w4[128 + lane];
        float4 hv = ((const float4*)h)[(size_t)wv * 64 + lane];
        float s0 = hv.x * w0.x + hv.y * w0.y + hv.z * w0.z + hv.w * w0.w;
        float s1 = hv.x * w1.x + hv.y * w1.y + hv.z * w1.z + hv.w * w1.w;
        float s2 = hv.x * w2v.x + hv.y * w2v.y + hv.z * w2v.z + hv.w * w2v.w;
#pragma unroll
        for (int off = 32; off; off >>= 1) {
            s0 += __shfl_down(s0, off);
            s1 += __shfl_down(s1, off);
            s2 += __shfl_down(s2, off);
        }
        if (lane == 0) { P0[wv] = s0; P1[wv] = s1; P2[wv] = s2; }
    }

    __shared__ int lastFlag;
    __syncthreads();              // drains this block's P stores
    if (tid == 0) {
        __threadfence();          // release: make P visible device-wide
        int old = atomicAdd(&done[b], 1);   // device-scope by default
        lastFlag = (old == 511);
    }
    __syncthreads();
    if (!lastFlag) return;
    __threadfence();              // acquire: see all siblings' P writes

    // ---- phase B: whole-batch scan (256 threads, 8 frames each) ----
    __shared__ float wsum[4];
    size_t base = (size_t)b * T;
    float bias = *bias2;
    int wlane = tid & 63, wid = tid >> 6;
    int t0 = tid * 8;
    float a[8];
    float s8 = 0.f;
#pragma unroll
    for (int j = 0; j < 8; ++j) {
        int t = t0 + j;
        size_t bt = base + t;
        float pre = P1[bt] + bias;
        if (t > 0)     pre += P0[bt - 1];
        if (t < T - 1) pre += P2[bt + 1];
        float av = 1.f / (1.f + expf(-pre));
        a[j] = av;
        s8 += av;
    }

    float x = s8;
#pragma unroll
    for (int off = 1; off < 64; off <<= 1) {
        float y = __shfl_up(x, off);
        if (wlane >= off) x += y;
    }
    if (wlane == 63) wsum[wid] = x;
    __syncthreads();              // orders P reads before F/A1/REM writes
    float woff = 0.f;
#pragma unroll
    for (int w = 0; w < 4; ++w)
        if (w < wid) woff += wsum[w];
    float Sprev = woff + (x - s8);   // exclusive prefix = S_{t0-1}

    if (tid == 0)
        lossP[b] = wsum[0] + wsum[1] + wsum[2] + wsum[3];

    int*   Fb = (int*)P0 + base;
    float* Ab = P1 + base;
    float* Rb = P2 + base;
#pragma unroll
    for (int j = 0; j < 8; ++j) {
        int t = t0 + j;
        float S  = Sprev + a[j];
        float kp = floorf(Sprev);
        float k  = floorf(S);
        if (k > kp) {                      // integer crossing => fire at t
            int ji = (int)kp;
            Fb[ji] = t;
            Ab[ji] = (kp + 1.0f) - Sprev;  // a1 = TH - aa_{t-1}
            Rb[ji] = S - k;                // rem carried into next cell
        }
        alpha[base + t] = a[j];
        Sprev = S;
    }
    if (tid == 255) {
        float K = floorf(Sprev);
        Kaux[2 * b]     = (int)K;
        Kaux[2 * b + 1] = (Sprev - K >= 0.5f) ? 1 : 0;
    }
}

// ---------------------------------------------------------------------------
// Kernel 3: gather. One wave per output row (b, j); lane owns 4 channels.
// out[j] = REM[j-1]*h[s] + sum_{s<t<e} alpha[t]*h[t] + A1[j]*h[e],
// accumulated in ascending-t order (matches reference hacc order).
// Rows past the fire count write zeros. Nontemporal stores keep the 33.5 MB
// output stream out of L2 so h re-reads stay cache-hot. Thread 0 also
// finalizes loss = sum of the 16 per-batch partials.
// ---------------------------------------------------------------------------
__global__ void gather_kernel(const float* __restrict__ h,
                              const float* __restrict__ alpha,
                              const int*   __restrict__ F,
                              const float* __restrict__ A1,
                              const float* __restrict__ REM,
                              const int*   __restrict__ Kaux,
                              const float* __restrict__ lossP,
                              float* __restrict__ out) {
    int gid  = blockIdx.x * blockDim.x + threadIdx.x;
    int wv   = gid >> 6;
    int lane = gid & 63;
    if (gid == 0) {
        float s = 0.f;
        for (int i = 0; i < B; ++i) s += lossP[i];
        out[(size_t)B * T * C] = s;
    }
    if (wv >= B * T) return;
    int b = wv >> 11;
    int j = wv & (T - 1);
    int K    = Kaux[2 * b];
    int tail = Kaux[2 * b + 1];
    vfloat4* orow = (vfloat4*)(out + ((size_t)b * T + j) * C) + lane;
    if (j > K || (j == K && !tail)) {
        vfloat4 z = {0.f, 0.f, 0.f, 0.f};
        __builtin_nontemporal_store(z, orow);
        return;
    }
    const float*  ab = alpha + (size_t)b * T;
    const float4* hb = (const float4*)(h + (size_t)b * T * C);
    const int*    Fb = F + (size_t)b * T;

    float4 acc;
    int t;
    if (j > 0) {
        int s = Fb[j - 1];
        float r = REM[(size_t)b * T + j - 1];
        float4 hv = hb[(size_t)s * 64 + lane];
        acc = make_float4(r * hv.x, r * hv.y, r * hv.z, r * hv.w);
        t = s + 1;
    } else {
        acc = make_float4(0.f, 0.f, 0.f, 0.f);
        t = 0;
    }
    int mid_end = (j == K) ? T : Fb[j];
    for (; t < mid_end; ++t) {
        float a = ab[t];
        float4 hv = hb[(size_t)t * 64 + lane];
        acc.x = fmaf(a, hv.x, acc.x);
        acc.y = fmaf(a, hv.y, acc.y);
        acc.z = fmaf(a, hv.z, acc.z);
        acc.w = fmaf(a, hv.w, acc.w);
    }
    if (j < K) {
        float a1 = A1[(size_t)b * T + j];
        float4 hv = hb[(size_t)mid_end * 64 + lane];
        acc.x = fmaf(a1, hv.x, acc.x);
        acc.y = fmaf(a1, hv.y, acc.y);
        acc.z = fmaf(a1, hv.z, acc.z);
        acc.w = fmaf(a1, hv.w, acc.w);
    }
    vfloat4 av = {acc.x, acc.y, acc.z, acc.w};
    __builtin_nontemporal_store(av, orow);
}

// ---------------------------------------------------------------------------
extern "C" void kernel_launch(void* const* d_in, const int* in_sizes, int n_in,
                              void* d_out, int out_size, void* d_ws, size_t ws_size,
                              hipStream_t stream) {
    const float* h      = (const float*)d_in[0];
    // d_in[1] = hs_mask (unused by the math)
    const float* conv_w = (const float*)d_in[2];
    const float* conv_b = (const float*)d_in[3];
    const float* lin_w  = (const float*)d_in[4];
    const float* lin_b  = (const float*)d_in[5];

    float* out = (float*)d_out;

    // workspace layout (floats):
    //   w2f[768] | bias2 (pad to 1024) | alpha[B*T] | P0[B*T] | P1[B*T]
    //   | P2[B*T] | Kaux[2B ints] | lossP[B] | done[B ints]
    float* w2f   = (float*)d_ws;
    float* bias2 = w2f + 768;
    float* alpha = w2f + 1024;
    float* P0    = alpha + B * T;
    float* P1    = P0 + B * T;
    float* P2    = P1 + B * T;
    int*   F     = (int*)P0;                  // alias (post-scan phase)
    float* A1    = P1;                        // alias
    float* REM   = P2;                        // alias
    int*   Kaux  = (int*)(P2 + B * T);        // 2*B ints
    float* lossP = (float*)(Kaux + 2 * B);    // B floats
    int*   done  = (int*)(lossP + B);         // B ints

    hipLaunchKernelGGL(w2_kernel, dim3(193), dim3(256), 0, stream,
                       conv_w, conv_b, lin_w, lin_b, w2f, bias2, done);

    hipLaunchKernelGGL(pdot_scan, dim3(B * T / 4), dim3(256), 0, stream,
                       h, w2f, bias2, P0, P1, P2, alpha, Kaux, lossP, done);

    hipLaunchKernelGGL(gather_kernel, dim3(B * T / 4), dim3(256), 0, stream,
                       h, alpha, F, A1, REM, Kaux, lossP, out);
}

// Round 8
// 38.151 us; speedup vs baseline: 7.3567x; 7.3567x over previous
//
#include <hip/hip_runtime.h>
#include <math.h>

constexpr int B = 16, T = 2048, C = 256;

typedef float vfloat4 __attribute__((ext_vector_type(4)));

// ---------------------------------------------------------------------------
// Kernel 1: fuse conv_w [C_out, C_in, 3] with lin_w [C_out] -> w2f[3*C], and
// bias2 = lin_w . conv_b + lin_b. One wave per output element (769 waves).
// w2f layout [k][i]: preact(t) = sum_i w2f[0][i]*h[t-1,i] + w2f[1][i]*h[t,i]
//                              + w2f[2][i]*h[t+1,i] + bias2
// ---------------------------------------------------------------------------
__global__ void w2_kernel(const float* __restrict__ conv_w,
                          const float* __restrict__ conv_b,
                          const float* __restrict__ lin_w,
                          const float* __restrict__ lin_b,
                          float* __restrict__ w2f,
                          float* __restrict__ bias2) {
    int gid  = blockIdx.x * blockDim.x + threadIdx.x;
    int wv   = gid >> 6;
    int lane = gid & 63;
    if (wv > 768) return;
    float s = 0.f;
    if (wv < 768) {
        int i = wv & 255, k = wv >> 8;   // wv = k*256 + i
#pragma unroll
        for (int m = 0; m < 4; ++m) {
            int o = lane + 64 * m;
            s = fmaf(lin_w[o], conv_w[((size_t)o * C + i) * 3 + k], s);
        }
    } else {
#pragma unroll
        for (int m = 0; m < 4; ++m) {
            int o = lane + 64 * m;
            s = fmaf(lin_w[o], conv_b[o], s);
        }
    }
#pragma unroll
    for (int off = 32; off; off >>= 1) s += __shfl_down(s, off);
    if (lane == 0) {
        if (wv < 768) w2f[wv] = s;
        else          *bias2 = s + lin_b[0];
    }
}

// ---------------------------------------------------------------------------
// Kernel 2: per-frame partial dots. One wave per (b,t); lane owns 4 channels.
// P_k[bt] = dot(w2f[k], h[b,t,:]).  h is read exactly once (32 MB).
// ---------------------------------------------------------------------------
__global__ void pdot_kernel(const float* __restrict__ h,
                            const float* __restrict__ w2f,
                            float* __restrict__ P0,
                            float* __restrict__ P1,
                            float* __restrict__ P2) {
    int gid  = blockIdx.x * blockDim.x + threadIdx.x;
    int wv   = gid >> 6;
    int lane = gid & 63;
    if (wv >= B * T) return;
    const float4* w4 = (const float4*)w2f;
    float4 w0 = w4[lane], w1 = w4[64 + lane], w2 = w4[128 + lane];
    float4 hv = ((const float4*)h)[(size_t)wv * 64 + lane];
    float s0 = hv.x * w0.x + hv.y * w0.y + hv.z * w0.z + hv.w * w0.w;
    float s1 = hv.x * w1.x + hv.y * w1.y + hv.z * w1.z + hv.w * w1.w;
    float s2 = hv.x * w2.x + hv.y * w2.y + hv.z * w2.z + hv.w * w2.w;
#pragma unroll
    for (int off = 32; off; off >>= 1) {
        s0 += __shfl_down(s0, off);
        s1 += __shfl_down(s1, off);
        s2 += __shfl_down(s2, off);
    }
    if (lane == 0) { P0[wv] = s0; P1[wv] = s1; P2[wv] = s2; }
}

// ---------------------------------------------------------------------------
// Kernel 3: fused alpha + loss partial + parallel fire computation via prefix
// sum. One block (256 threads) per batch row; 8 frames per thread.
//   aa_t == S_t - floor(S_t)  where S is the prefix sum of alpha, so
//   fire at t  <=>  floor(S_t) > floor(S_{t-1}),  fire index j = floor(S_{t-1}),
//   a1 = (j+1) - S_{t-1},  rem = S_t - floor(S_t),
//   K = floor(S_{T-1}),  tail = (S_{T-1} - K) >= 0.5.
// F/A1/REM alias P0/P1/P2: all P reads precede the __syncthreads(), all
// F/A1/REM writes follow it, and each block touches only its own batch range.
// Writes lossP[b] (summed by gather) -> no loss memset dispatch needed.
// ---------------------------------------------------------------------------
__global__ void scan_kernel(const float* __restrict__ P0,
                            const float* __restrict__ P1,
                            const float* __restrict__ P2,
                            const float* __restrict__ bias2,
                            float* __restrict__ alpha,
                            int*   __restrict__ F,
                            float* __restrict__ A1,
                            float* __restrict__ REM,
                            int*   __restrict__ Kaux,
                            float* __restrict__ lossP) {
    __shared__ float wsum[4];
    int b    = blockIdx.x;
    int tid  = threadIdx.x;        // 0..255
    int lane = tid & 63, wid = tid >> 6;
    size_t base = (size_t)b * T;
    float bias = *bias2;

    // ---- phase 1: alpha for this thread's 8 frames (all P reads here) ----
    int t0 = tid * 8;
    float a[8];
    float s8 = 0.f;
#pragma unroll
    for (int j = 0; j < 8; ++j) {
        int t = t0 + j;
        size_t bt = base + t;
        float pre = P1[bt] + bias;
        if (t > 0)     pre += P0[bt - 1];
        if (t < T - 1) pre += P2[bt + 1];
        float av = 1.f / (1.f + expf(-pre));
        a[j] = av;
        s8 += av;
    }

    // ---- block-level exclusive scan of per-thread sums ----
    float x = s8;
#pragma unroll
    for (int off = 1; off < 64; off <<= 1) {
        float y = __shfl_up(x, off);
        if (lane >= off) x += y;
    }
    if (lane == 63) wsum[wid] = x;
    __syncthreads();                       // also orders P reads before F writes
    float woff = 0.f;
#pragma unroll
    for (int w = 0; w < 4; ++w)
        if (w < wid) woff += wsum[w];
    float Sprev = woff + (x - s8);         // exclusive prefix = S_{t0-1}

    if (tid == 0)
        lossP[b] = wsum[0] + wsum[1] + wsum[2] + wsum[3];

    // ---- phase 2: per-frame fire detection + writes ----
    int*   Fb = F   + base;
    float* Ab = A1  + base;
    float* Rb = REM + base;
#pragma unroll
    for (int j = 0; j < 8; ++j) {
        int t = t0 + j;
        float S  = Sprev + a[j];
        float kp = floorf(Sprev);
        float k  = floorf(S);
        if (k > kp) {                      // integer crossing => fire at t
            int ji = (int)kp;
            Fb[ji] = t;
            Ab[ji] = (kp + 1.0f) - Sprev;  // a1 = TH - aa_{t-1}
            Rb[ji] = S - k;                // rem carried into next cell
        }
        alpha[base + t] = a[j];
        Sprev = S;
    }
    if (tid == 255) {
        float K = floorf(Sprev);
        Kaux[2 * b]     = (int)K;
        Kaux[2 * b + 1] = (Sprev - K >= 0.5f) ? 1 : 0;
    }
}

// ---------------------------------------------------------------------------
// Kernel 4: gather. One wave per output row (b, j); lane owns 4 channels.
// out[j] = REM[j-1]*h[s] + sum_{s<t<e} alpha[t]*h[t] + A1[j]*h[e],
// accumulated in ascending-t order (matches reference hacc order).
// Rows past the fire count write zeros. Nontemporal stores keep the 33.5 MB
// output stream from evicting h in L2. Thread 0 finalizes loss from lossP.
// ---------------------------------------------------------------------------
__global__ void gather_kernel(const float* __restrict__ h,
                              const float* __restrict__ alpha,
                              const int*   __restrict__ F,
                              const float* __restrict__ A1,
                              const float* __restrict__ REM,
                              const int*   __restrict__ Kaux,
                              const float* __restrict__ lossP,
                              float* __restrict__ out) {
    int gid  = blockIdx.x * blockDim.x + threadIdx.x;
    int wv   = gid >> 6;
    int lane = gid & 63;
    if (gid == 0) {
        float s = 0.f;
        for (int i = 0; i < B; ++i) s += lossP[i];
        out[(size_t)B * T * C] = s;
    }
    if (wv >= B * T) return;
    int b = wv >> 11;
    int j = wv & (T - 1);
    int K    = Kaux[2 * b];
    int tail = Kaux[2 * b + 1];
    vfloat4* orow = (vfloat4*)(out + ((size_t)b * T + j) * C) + lane;
    if (j > K || (j == K && !tail)) {
        vfloat4 z = {0.f, 0.f, 0.f, 0.f};
        __builtin_nontemporal_store(z, orow);
        return;
    }
    const float*  ab = alpha + (size_t)b * T;
    const float4* hb = (const float4*)(h + (size_t)b * T * C);
    const int*    Fb = F + (size_t)b * T;

    float4 acc;
    int t;
    if (j > 0) {
        int s = Fb[j - 1];
        float r = REM[(size_t)b * T + j - 1];
        float4 hv = hb[(size_t)s * 64 + lane];
        acc = make_float4(r * hv.x, r * hv.y, r * hv.z, r * hv.w);
        t = s + 1;
    } else {
        acc = make_float4(0.f, 0.f, 0.f, 0.f);
        t = 0;
    }
    int mid_end = (j == K) ? T : Fb[j];
    for (; t < mid_end; ++t) {
        float a = ab[t];
        float4 hv = hb[(size_t)t * 64 + lane];
        acc.x = fmaf(a, hv.x, acc.x);
        acc.y = fmaf(a, hv.y, acc.y);
        acc.z = fmaf(a, hv.z, acc.z);
        acc.w = fmaf(a, hv.w, acc.w);
    }
    if (j < K) {
        float a1 = A1[(size_t)b * T + j];
        float4 hv = hb[(size_t)mid_end * 64 + lane];
        acc.x = fmaf(a1, hv.x, acc.x);
        acc.y = fmaf(a1, hv.y, acc.y);
        acc.z = fmaf(a1, hv.z, acc.z);
        acc.w = fmaf(a1, hv.w, acc.w);
    }
    vfloat4 av = {acc.x, acc.y, acc.z, acc.w};
    __builtin_nontemporal_store(av, orow);
}

// ---------------------------------------------------------------------------
extern "C" void kernel_launch(void* const* d_in, const int* in_sizes, int n_in,
                              void* d_out, int out_size, void* d_ws, size_t ws_size,
                              hipStream_t stream) {
    const float* h      = (const float*)d_in[0];
    // d_in[1] = hs_mask (unused by the math)
    const float* conv_w = (const float*)d_in[2];
    const float* conv_b = (const float*)d_in[3];
    const float* lin_w  = (const float*)d_in[4];
    const float* lin_b  = (const float*)d_in[5];

    float* out = (float*)d_out;

    // workspace layout (floats):
    //   w2f[768] | bias2 (pad to 1024) | alpha[B*T] | P0[B*T] | P1[B*T]
    //   | P2[B*T] | Kaux[2B ints] | lossP[B]
    // F/A1/REM alias P0/P1/P2 (safe: see scan_kernel comment).
    float* w2f   = (float*)d_ws;
    float* bias2 = w2f + 768;
    float* alpha = w2f + 1024;
    float* P0    = alpha + B * T;
    float* P1    = P0 + B * T;
    float* P2    = P1 + B * T;
    int*   F     = (int*)P0;
    float* A1    = P1;
    float* REM   = P2;
    int*   Kaux  = (int*)(P2 + B * T);        // 2*B ints
    float* lossP = (float*)(Kaux + 2 * B);    // B floats

    hipLaunchKernelGGL(w2_kernel, dim3(193), dim3(256), 0, stream,
                       conv_w, conv_b, lin_w, lin_b, w2f, bias2);

    hipLaunchKernelGGL(pdot_kernel, dim3(B * T / 4), dim3(256), 0, stream,
                       h, w2f, P0, P1, P2);

    hipLaunchKernelGGL(scan_kernel, dim3(B), dim3(256), 0, stream,
                       P0, P1, P2, bias2, alpha, F, A1, REM, Kaux, lossP);

    hipLaunchKernelGGL(gather_kernel, dim3(B * T / 4), dim3(256), 0, stream,
                       h, alpha, F, A1, REM, Kaux, lossP, out);
}

// Round 9
// 36.683 us; speedup vs baseline: 7.6512x; 1.0400x over previous
//
#include <hip/hip_runtime.h>
#include <math.h>

constexpr int B = 16, T = 2048, C = 256;

typedef float vfloat4 __attribute__((ext_vector_type(4)));

// ---------------------------------------------------------------------------
// Kernel 1: fuse conv_w [C_out, C_in, 3] with lin_w [C_out] -> w2f[3*C], and
// bias2 = lin_w . conv_b + lin_b. One wave per output element (769 waves).
// w2f layout [k][i]: preact(t) = sum_i w2f[0][i]*h[t-1,i] + w2f[1][i]*h[t,i]
//                              + w2f[2][i]*h[t+1,i] + bias2
// ---------------------------------------------------------------------------
__global__ void w2_kernel(const float* __restrict__ conv_w,
                          const float* __restrict__ conv_b,
                          const float* __restrict__ lin_w,
                          const float* __restrict__ lin_b,
                          float* __restrict__ w2f,
                          float* __restrict__ bias2) {
    int gid  = blockIdx.x * blockDim.x + threadIdx.x;
    int wv   = gid >> 6;
    int lane = gid & 63;
    if (wv > 768) return;
    float s = 0.f;
    if (wv < 768) {
        int i = wv & 255, k = wv >> 8;   // wv = k*256 + i
#pragma unroll
        for (int m = 0; m < 4; ++m) {
            int o = lane + 64 * m;
            s = fmaf(lin_w[o], conv_w[((size_t)o * C + i) * 3 + k], s);
        }
    } else {
#pragma unroll
        for (int m = 0; m < 4; ++m) {
            int o = lane + 64 * m;
            s = fmaf(lin_w[o], conv_b[o], s);
        }
    }
#pragma unroll
    for (int off = 32; off; off >>= 1) s += __shfl_down(s, off);
    if (lane == 0) {
        if (wv < 768) w2f[wv] = s;
        else          *bias2 = s + lin_b[0];
    }
}

// ---------------------------------------------------------------------------
// Kernel 2: per-frame partial dots, 16-LANE-GROUP layout.
// Each wave: 4 groups of 16 lanes; a group owns one frame per chunk; lane
// covers 16 channels (4 x float4). Weights hoisted to 12 float4 registers,
// amortized over FPW=8 frames/wave. Reduction = 4 shfl_xor levels within the
// 16-lane group (3 shuffles/frame vs 18 in the 64-lane version).
// P_k[bt] = dot(w2f[k], h[b,t,:]); h read exactly once (32 MB).
// ---------------------------------------------------------------------------
constexpr int FPW = 8;  // frames per wave
__global__ void pdot_kernel(const float* __restrict__ h,
                            const float* __restrict__ w2f,
                            float* __restrict__ P0,
                            float* __restrict__ P1,
                            float* __restrict__ P2) {
    int gid  = blockIdx.x * blockDim.x + threadIdx.x;
    int wave = gid >> 6;
    int lane = gid & 63;
    int g    = lane >> 4;      // group 0..3 (frame within chunk)
    int il   = lane & 15;      // lane within group (16 channels)

    const float4* w4 = (const float4*)w2f;   // [3][64] float4
    float4 W0[4], W1[4], W2[4];
#pragma unroll
    for (int m = 0; m < 4; ++m) {
        W0[m] = w4[il * 4 + m];
        W1[m] = w4[64 + il * 4 + m];
        W2[m] = w4[128 + il * 4 + m];
    }

    int frame0 = wave * FPW;
#pragma unroll
    for (int chunk = 0; chunk < FPW / 4; ++chunk) {
        int f = frame0 + chunk * 4 + g;      // this group's frame
        const float4* hf = (const float4*)(h + (size_t)f * C);
        float s0 = 0.f, s1 = 0.f, s2 = 0.f;
#pragma unroll
        for (int m = 0; m < 4; ++m) {
            float4 hv = hf[il * 4 + m];
            s0 = fmaf(hv.x, W0[m].x, fmaf(hv.y, W0[m].y,
                 fmaf(hv.z, W0[m].z, fmaf(hv.w, W0[m].w, s0))));
            s1 = fmaf(hv.x, W1[m].x, fmaf(hv.y, W1[m].y,
                 fmaf(hv.z, W1[m].z, fmaf(hv.w, W1[m].w, s1))));
            s2 = fmaf(hv.x, W2[m].x, fmaf(hv.y, W2[m].y,
                 fmaf(hv.z, W2[m].z, fmaf(hv.w, W2[m].w, s2))));
        }
#pragma unroll
        for (int off = 8; off; off >>= 1) {
            s0 += __shfl_xor(s0, off, 16);
            s1 += __shfl_xor(s1, off, 16);
            s2 += __shfl_xor(s2, off, 16);
        }
        if (il == 0) { P0[f] = s0; P1[f] = s1; P2[f] = s2; }
    }
}

// ---------------------------------------------------------------------------
// Kernel 3: fused alpha + loss partial + parallel fire computation via prefix
// sum. One block (256 threads) per batch row; 8 frames per thread.
//   aa_t == S_t - floor(S_t)  where S is the prefix sum of alpha, so
//   fire at t  <=>  floor(S_t) > floor(S_{t-1}),  fire index j = floor(S_{t-1}),
//   a1 = (j+1) - S_{t-1},  rem = S_t - floor(S_t),
//   K = floor(S_{T-1}),  tail = (S_{T-1} - K) >= 0.5.
// F/A1/REM alias P0/P1/P2: all P reads precede the __syncthreads(), all
// F/A1/REM writes follow it, and each block touches only its own batch range.
// ---------------------------------------------------------------------------
__global__ void scan_kernel(const float* __restrict__ P0,
                            const float* __restrict__ P1,
                            const float* __restrict__ P2,
                            const float* __restrict__ bias2,
                            float* __restrict__ alpha,
                            int*   __restrict__ F,
                            float* __restrict__ A1,
                            float* __restrict__ REM,
                            int*   __restrict__ Kaux,
                            float* __restrict__ lossP) {
    __shared__ float wsum[4];
    int b    = blockIdx.x;
    int tid  = threadIdx.x;        // 0..255
    int lane = tid & 63, wid = tid >> 6;
    size_t base = (size_t)b * T;
    float bias = *bias2;

    // ---- phase 1: alpha for this thread's 8 frames (all P reads here) ----
    int t0 = tid * 8;
    float a[8];
    float s8 = 0.f;
#pragma unroll
    for (int j = 0; j < 8; ++j) {
        int t = t0 + j;
        size_t bt = base + t;
        float pre = P1[bt] + bias;
        if (t > 0)     pre += P0[bt - 1];
        if (t < T - 1) pre += P2[bt + 1];
        float av = 1.f / (1.f + expf(-pre));
        a[j] = av;
        s8 += av;
    }

    // ---- block-level exclusive scan of per-thread sums ----
    float x = s8;
#pragma unroll
    for (int off = 1; off < 64; off <<= 1) {
        float y = __shfl_up(x, off);
        if (lane >= off) x += y;
    }
    if (lane == 63) wsum[wid] = x;
    __syncthreads();                       // also orders P reads before F writes
    float woff = 0.f;
#pragma unroll
    for (int w = 0; w < 4; ++w)
        if (w < wid) woff += wsum[w];
    float Sprev = woff + (x - s8);         // exclusive prefix = S_{t0-1}

    if (tid == 0)
        lossP[b] = wsum[0] + wsum[1] + wsum[2] + wsum[3];

    // ---- phase 2: per-frame fire detection + writes ----
    int*   Fb = F   + base;
    float* Ab = A1  + base;
    float* Rb = REM + base;
#pragma unroll
    for (int j = 0; j < 8; ++j) {
        int t = t0 + j;
        float S  = Sprev + a[j];
        float kp = floorf(Sprev);
        float k  = floorf(S);
        if (k > kp) {                      // integer crossing => fire at t
            int ji = (int)kp;
            Fb[ji] = t;
            Ab[ji] = (kp + 1.0f) - Sprev;  // a1 = TH - aa_{t-1}
            Rb[ji] = S - k;                // rem carried into next cell
        }
        alpha[base + t] = a[j];
        Sprev = S;
    }
    if (tid == 255) {
        float K = floorf(Sprev);
        Kaux[2 * b]     = (int)K;
        Kaux[2 * b + 1] = (Sprev - K >= 0.5f) ? 1 : 0;
    }
}

// ---------------------------------------------------------------------------
// Kernel 4: gather. One wave per output row (b, j); lane owns 4 channels.
// out[j] = REM[j-1]*h[s] + sum_{s<t<e} alpha[t]*h[t] + A1[j]*h[e],
// accumulated in ascending-t order (matches reference hacc order).
// Rows past the fire count write zeros. Nontemporal stores keep the 33.5 MB
// output stream from evicting h in L2. Thread 0 finalizes loss from lossP.
// ---------------------------------------------------------------------------
__global__ void gather_kernel(const float* __restrict__ h,
                              const float* __restrict__ alpha,
                              const int*   __restrict__ F,
                              const float* __restrict__ A1,
                              const float* __restrict__ REM,
                              const int*   __restrict__ Kaux,
                              const float* __restrict__ lossP,
                              float* __restrict__ out) {
    int gid  = blockIdx.x * blockDim.x + threadIdx.x;
    int wv   = gid >> 6;
    int lane = gid & 63;
    if (gid == 0) {
        float s = 0.f;
        for (int i = 0; i < B; ++i) s += lossP[i];
        out[(size_t)B * T * C] = s;
    }
    if (wv >= B * T) return;
    int b = wv >> 11;
    int j = wv & (T - 1);
    int K    = Kaux[2 * b];
    int tail = Kaux[2 * b + 1];
    vfloat4* orow = (vfloat4*)(out + ((size_t)b * T + j) * C) + lane;
    if (j > K || (j == K && !tail)) {
        vfloat4 z = {0.f, 0.f, 0.f, 0.f};
        __builtin_nontemporal_store(z, orow);
        return;
    }
    const float*  ab = alpha + (size_t)b * T;
    const float4* hb = (const float4*)(h + (size_t)b * T * C);
    const int*    Fb = F + (size_t)b * T;

    float4 acc;
    int t;
    if (j > 0) {
        int s = Fb[j - 1];
        float r = REM[(size_t)b * T + j - 1];
        float4 hv = hb[(size_t)s * 64 + lane];
        acc = make_float4(r * hv.x, r * hv.y, r * hv.z, r * hv.w);
        t = s + 1;
    } else {
        acc = make_float4(0.f, 0.f, 0.f, 0.f);
        t = 0;
    }
    int mid_end = (j == K) ? T : Fb[j];
    for (; t < mid_end; ++t) {
        float a = ab[t];
        float4 hv = hb[(size_t)t * 64 + lane];
        acc.x = fmaf(a, hv.x, acc.x);
        acc.y = fmaf(a, hv.y, acc.y);
        acc.z = fmaf(a, hv.z, acc.z);
        acc.w = fmaf(a, hv.w, acc.w);
    }
    if (j < K) {
        float a1 = A1[(size_t)b * T + j];
        float4 hv = hb[(size_t)mid_end * 64 + lane];
        acc.x = fmaf(a1, hv.x, acc.x);
        acc.y = fmaf(a1, hv.y, acc.y);
        acc.z = fmaf(a1, hv.z, acc.z);
        acc.w = fmaf(a1, hv.w, acc.w);
    }
    vfloat4 av = {acc.x, acc.y, acc.z, acc.w};
    __builtin_nontemporal_store(av, orow);
}

// ---------------------------------------------------------------------------
extern "C" void kernel_launch(void* const* d_in, const int* in_sizes, int n_in,
                              void* d_out, int out_size, void* d_ws, size_t ws_size,
                              hipStream_t stream) {
    const float* h      = (const float*)d_in[0];
    // d_in[1] = hs_mask (unused by the math)
    const float* conv_w = (const float*)d_in[2];
    const float* conv_b = (const float*)d_in[3];
    const float* lin_w  = (const float*)d_in[4];
    const float* lin_b  = (const float*)d_in[5];

    float* out = (float*)d_out;

    // workspace layout (floats):
    //   w2f[768] | bias2 (pad to 1024) | alpha[B*T] | P0[B*T] | P1[B*T]
    //   | P2[B*T] | Kaux[2B ints] | lossP[B]
    // F/A1/REM alias P0/P1/P2 (safe: see scan_kernel comment).
    float* w2f   = (float*)d_ws;
    float* bias2 = w2f + 768;
    float* alpha = w2f + 1024;
    float* P0    = alpha + B * T;
    float* P1    = P0 + B * T;
    float* P2    = P1 + B * T;
    int*   F     = (int*)P0;
    float* A1    = P1;
    float* REM   = P2;
    int*   Kaux  = (int*)(P2 + B * T);        // 2*B ints
    float* lossP = (float*)(Kaux + 2 * B);    // B floats

    hipLaunchKernelGGL(w2_kernel, dim3(193), dim3(256), 0, stream,
                       conv_w, conv_b, lin_w, lin_b, w2f, bias2);

    // 4 waves/block, FPW frames/wave -> B*T / (4*FPW) blocks
    hipLaunchKernelGGL(pdot_kernel, dim3(B * T / (4 * FPW)), dim3(256), 0, stream,
                       h, w2f, P0, P1, P2);

    hipLaunchKernelGGL(scan_kernel, dim3(B), dim3(256), 0, stream,
                       P0, P1, P2, bias2, alpha, F, A1, REM, Kaux, lossP);

    hipLaunchKernelGGL(gather_kernel, dim3(B * T / 4), dim3(256), 0, stream,
                       h, alpha, F, A1, REM, Kaux, lossP, out);
}